// Round 1
// baseline (40.968 us; speedup 1.0000x reference)
//
#include <hip/hip_runtime.h>

#define LDIM 512
#define SITES (LDIM * LDIM)

__device__ __forceinline__ float spin_of(float x0, float x1) {
    // argmax tie-break: index 0 wins on equality -> spin -1
    return x1 > x0 ? 1.0f : -1.0f;
}

// Each block: one batch slice of 4 rows (4 x 512 sites). 256 threads,
// 8 consecutive sites per thread. Emits one float4 partial {A, Hs, T1, T2}.
__global__ __launch_bounds__(256) void ising_partial(
        const float* __restrict__ x, float4* __restrict__ part) {
    const int b    = blockIdx.y;
    const int rblk = blockIdx.x;              // 0..127, 4 rows each
    const int t    = threadIdx.x;
    const int row  = rblk * 4 + (t >> 6);
    const int tcol = t & 63;                  // 8 sites per thread

    const float* xb   = x + (size_t)b * (size_t)(SITES * 2);
    const float* rown = xb + row * (LDIM * 2);
    const float* rowu = xb + ((row + LDIM - 1) & (LDIM - 1)) * (LDIM * 2);
    const float* rowd = xb + ((row + 1) & (LDIM - 1)) * (LDIM * 2);

    float sx0[8], sx1[8], so[8], su[8], sd[8];

    const float4* pn = (const float4*)rown;
    const float4* pu = (const float4*)rowu;
    const float4* pd = (const float4*)rowd;
    #pragma unroll
    for (int q = 0; q < 4; ++q) {
        float4 v = pn[tcol * 4 + q];          // 2 sites: {x0,x1,x0,x1}
        sx0[2*q]   = v.x; sx1[2*q]   = v.y;
        sx0[2*q+1] = v.z; sx1[2*q+1] = v.w;
        float4 a = pu[tcol * 4 + q];
        su[2*q]   = spin_of(a.x, a.y);
        su[2*q+1] = spin_of(a.z, a.w);
        float4 c = pd[tcol * 4 + q];
        sd[2*q]   = spin_of(c.x, c.y);
        sd[2*q+1] = spin_of(c.z, c.w);
    }
    #pragma unroll
    for (int k = 0; k < 8; ++k) so[k] = spin_of(sx0[k], sx1[k]);

    const int col0 = tcol << 3;
    const float2 lv = ((const float2*)rown)[(col0 + LDIM - 1) & (LDIM - 1)];
    const float2 rv = ((const float2*)rown)[(col0 + 8) & (LDIM - 1)];
    const float sl = spin_of(lv.x, lv.y);
    const float sr = spin_of(rv.x, rv.y);

    float A = 0.f, Hs = 0.f, T1 = 0.f, T2 = 0.f;
    #pragma unroll
    for (int k = 0; k < 8; ++k) {
        const float lft = (k == 0) ? sl : so[k - 1];
        const float rgt = (k == 7) ? sr : so[k + 1];
        const float h   = lft + rgt + su[k] + sd[k];
        const float sh  = so[k] * h;
        const float a   = sx0[k] + sx1[k];
        const float d   = sx0[k] - sx1[k];
        A  += a;
        Hs += sh;
        T1 += a * sh;
        T2 += d * h;
    }

    // wave64 shuffle reduction, then cross-wave via LDS
    #pragma unroll
    for (int off = 32; off; off >>= 1) {
        A  += __shfl_down(A,  off);
        Hs += __shfl_down(Hs, off);
        T1 += __shfl_down(T1, off);
        T2 += __shfl_down(T2, off);
    }

    __shared__ float4 red[4];
    if ((t & 63) == 0) red[t >> 6] = make_float4(A, Hs, T1, T2);
    __syncthreads();
    if (t == 0) {
        float4 r = red[0];
        #pragma unroll
        for (int w = 1; w < 4; ++w) {
            float4 q = red[w];
            r.x += q.x; r.y += q.y; r.z += q.z; r.w += q.w;
        }
        part[b * 128 + rblk] = r;
    }
}

// One block per batch: reduce 128 partials, apply closed form.
__global__ __launch_bounds__(128) void ising_final(
        const float4* __restrict__ part, float* __restrict__ out) {
    const int b = blockIdx.x;
    const int t = threadIdx.x;
    float4 v = part[b * 128 + t];
    float A = v.x, Hs = v.y, T1 = v.z, T2 = v.w;
    #pragma unroll
    for (int off = 32; off; off >>= 1) {
        A  += __shfl_down(A,  off);
        Hs += __shfl_down(Hs, off);
        T1 += __shfl_down(T1, off);
        T2 += __shfl_down(T2, off);
    }
    __shared__ float4 red[2];
    if ((t & 63) == 0) red[t >> 6] = make_float4(A, Hs, T1, T2);
    __syncthreads();
    if (t == 0) {
        float4 q = red[1];
        A += q.x; Hs += q.y; T1 += q.z; T2 += q.w;
        const float total = -0.5f * Hs * A + T1 + T2;
        out[b] = total * (1.0f / (float)SITES);
    }
}

extern "C" void kernel_launch(void* const* d_in, const int* in_sizes, int n_in,
                              void* d_out, int out_size, void* d_ws, size_t ws_size,
                              hipStream_t stream) {
    const float* x = (const float*)d_in[0];
    float* out = (float*)d_out;
    float4* part = (float4*)d_ws;   // B * 128 float4 partials (128 KiB for B=64)

    const int B = in_sizes[0] / (SITES * 2);

    dim3 grid(128, B);
    ising_partial<<<grid, 256, 0, stream>>>(x, part);
    ising_final<<<B, 128, 0, stream>>>(part, out);
}

// Round 2
// 29.227 us; speedup vs baseline: 1.4017x; 1.4017x over previous
//
#include <hip/hip_runtime.h>

#define LDIM 512
#define SITES (LDIM * LDIM)
#define H 16                    // rows per strip (per wave)
#define STRIPS (LDIM / H)       // 32 strips per batch
#define WPB 4                   // waves per block

__device__ __forceinline__ float spin_of(float x0, float x1) {
    // argmax tie-break: index 0 wins on equality -> spin -1
    return x1 > x0 ? 1.0f : -1.0f;
}

// One wave per strip: 64 lanes x 8 cols = full 512-wide row. Walks H rows
// with a 3-row rolling spin window; every row loaded exactly once (+2 halos).
__global__ __launch_bounds__(256) void ising_strip(
        const float* __restrict__ x, float4* __restrict__ part) {
    const int b     = blockIdx.y;
    const int wave  = threadIdx.x >> 6;
    const int lane  = threadIdx.x & 63;
    const int strip = blockIdx.x * WPB + wave;
    const int r0    = strip * H;

    const float* xb = x + (size_t)b * (size_t)(SITES * 2);

    float4 xv[2][4];   // ping-pong x buffers (row being consumed / row loading)
    float  sp[3][8];   // rolling spins: rows r-1, r, r+1
    float A = 0.f, Hs = 0.f, T1 = 0.f, T2 = 0.f;

    #define LOADROW(row, dst)                                                  \
        {                                                                      \
            const float4* p_ =                                                 \
                (const float4*)(xb + (size_t)(row) * (LDIM * 2));              \
            _Pragma("unroll")                                                  \
            for (int q_ = 0; q_ < 4; ++q_) (dst)[q_] = p_[lane * 4 + q_];      \
        }
    #define SPINS(v, s)                                                        \
        {                                                                      \
            _Pragma("unroll")                                                  \
            for (int q_ = 0; q_ < 4; ++q_) {                                   \
                (s)[2 * q_]     = spin_of((v)[q_].x, (v)[q_].y);               \
                (s)[2 * q_ + 1] = spin_of((v)[q_].z, (v)[q_].w);               \
            }                                                                  \
        }

    // prologue: halo row r0-1 -> sp[0]; row r0 -> xv[0], spins -> sp[1]
    {
        float4 tmp[4];
        LOADROW((r0 + LDIM - 1) & (LDIM - 1), tmp);
        SPINS(tmp, sp[0]);
        LOADROW(r0, xv[0]);
        SPINS(xv[0], sp[1]);
    }

    const int laneL = (lane + 63) & 63;
    const int laneR = (lane + 1) & 63;

    #pragma unroll
    for (int i = 0; i < H; ++i) {
        const int cur = i & 1;          // xv slot holding row r0+i
        const int nxt = (i + 1) & 1;
        LOADROW((r0 + i + 1) & (LDIM - 1), xv[nxt]);
        float* sP = sp[i % 3];          // row r0+i-1
        float* sC = sp[(i + 1) % 3];    // row r0+i
        float* sN = sp[(i + 2) % 3];    // row r0+i+1
        SPINS(xv[nxt], sN);

        const float sl = __shfl(sC[7], laneL);  // torus row wrap via full-wave row
        const float sr = __shfl(sC[0], laneR);

        #pragma unroll
        for (int k = 0; k < 8; ++k) {
            const float lft = (k == 0) ? sl : sC[k - 1];
            const float rgt = (k == 7) ? sr : sC[k + 1];
            const float h   = lft + rgt + sP[k] + sN[k];
            const float4 v  = xv[cur][k >> 1];
            const float x0  = (k & 1) ? v.z : v.x;
            const float x1  = (k & 1) ? v.w : v.y;
            const float a   = x0 + x1;
            const float d   = x0 - x1;
            const float sh  = sC[k] * h;
            A  += a;
            Hs += sh;
            T1 += a * sh;
            T2 += d * h;
        }
    }

    #pragma unroll
    for (int off = 32; off; off >>= 1) {
        A  += __shfl_down(A,  off);
        Hs += __shfl_down(Hs, off);
        T1 += __shfl_down(T1, off);
        T2 += __shfl_down(T2, off);
    }
    if (lane == 0) part[b * STRIPS + strip] = make_float4(A, Hs, T1, T2);

    #undef LOADROW
    #undef SPINS
}

// One block (single wave) per batch: reduce STRIPS partials, apply closed form.
__global__ __launch_bounds__(64) void ising_final(
        const float4* __restrict__ part, float* __restrict__ out) {
    const int b = blockIdx.x;
    const int t = threadIdx.x;
    float A = 0.f, Hs = 0.f, T1 = 0.f, T2 = 0.f;
    if (t < STRIPS) {
        float4 v = part[b * STRIPS + t];
        A = v.x; Hs = v.y; T1 = v.z; T2 = v.w;
    }
    #pragma unroll
    for (int off = 32; off; off >>= 1) {
        A  += __shfl_down(A,  off);
        Hs += __shfl_down(Hs, off);
        T1 += __shfl_down(T1, off);
        T2 += __shfl_down(T2, off);
    }
    if (t == 0) {
        const float total = -0.5f * Hs * A + T1 + T2;
        out[b] = total * (1.0f / (float)SITES);
    }
}

extern "C" void kernel_launch(void* const* d_in, const int* in_sizes, int n_in,
                              void* d_out, int out_size, void* d_ws, size_t ws_size,
                              hipStream_t stream) {
    const float* x = (const float*)d_in[0];
    float* out = (float*)d_out;
    float4* part = (float4*)d_ws;   // B * STRIPS float4 partials (32 KiB for B=64)

    const int B = in_sizes[0] / (SITES * 2);

    dim3 grid(STRIPS / WPB, B);     // 8 x 64 = 512 blocks, 4 waves each
    ising_strip<<<grid, WPB * 64, 0, stream>>>(x, part);
    ising_final<<<B, 64, 0, stream>>>(part, out);
}